// Round 6
// baseline (109.110 us; speedup 1.0000x reference)
//
#include <hip/hip_runtime.h>
#include <math.h>

typedef __attribute__((ext_vector_type(8))) short short8;
typedef __attribute__((ext_vector_type(4))) float float4v;
typedef __attribute__((ext_vector_type(4))) unsigned int uint4v;

#define GH_ 256
#define GW_ 256
#define H_  128
#define W_  128
#define C_  64
#define OC_ 64
#define NB_ 4

static __device__ __forceinline__ unsigned short f2bf(float f) {
    union { float f; unsigned int u; } v; v.f = f;
    unsigned int u = v.u;
    unsigned int r = u + 0x7FFFu + ((u >> 16) & 1u);   // round-to-nearest-even
    return (unsigned short)(r >> 16);
}

// XOR swizzle within each 128B "col row" of xt: spreads the per-col 128B stride
// across 8 16B bank-group slots. Applied identically on write and read.
static __device__ __forceinline__ int swz(int byte) {
    return byte ^ (((byte >> 7) & 7) << 4);
}

// Single fused kernel. Weight pack is done in-kernel by the first 9 blocks to
// draw a ticket (guaranteed-running -> deadlock-free); all blocks spin on an
// agent-scope done-counter AFTER their transpose+klds phase, so pack latency
// hides under phase 0 of the other 255 blocks.
// flags[0] = ticket counter, flags[1] = done counter (memset to 0 pre-launch).
__global__ __launch_bounds__(1024, 4) void pac_fused(
    const float* __restrict__ x,
    const float* __restrict__ guide,
    const float* __restrict__ wgt,
    const float* __restrict__ bias,
    unsigned short* __restrict__ wtb,
    unsigned int* __restrict__ flags,
    float* __restrict__ out)
{
    __shared__ unsigned short xt[3 * 128 * 64];   // 49152 B, swizzled [lr][col][c] bf16
    __shared__ float klds[9][2][128];             // 9216 B
    __shared__ unsigned int sticket;

    const int ypair = blockIdx.x;   // 0..63
    const int b     = blockIdx.y;   // 0..3
    const int tid   = threadIdx.x;
    const int R0    = ypair * 2;

    // ---------------- phase -1: ticketed weight pack (9 winner blocks) ----------
    if (tid == 0)
        sticket = __hip_atomic_fetch_add(&flags[0], 1u, __ATOMIC_RELAXED,
                                         __HIP_MEMORY_SCOPE_AGENT);
    __syncthreads();
    if (sticket < 9u) {
        const int t = (int)sticket;              // tap = kh*3+kw
        for (int i = tid; i < OC_ * C_; i += 1024) {
            int c = i & 63, o = (i >> 6) & 63;
            wtb[t * OC_ * C_ + i] = f2bf(wgt[(c * OC_ + o) * 9 + t]);
        }
        __syncthreads();                          // block-uniform condition: legal
        if (tid == 0) {
            __threadfence();                      // write back before signaling
            __hip_atomic_fetch_add(&flags[1], 1u, __ATOMIC_RELEASE,
                                   __HIP_MEMORY_SCOPE_AGENT);
        }
    }

    // ---------------- phase 0a: direct transpose x -> xt ----------------
    {
        const int col = tid & 127;          // source iw / xt row
        const int cg  = tid >> 7;           // channel group 0..7 (8 ch each)
        #pragma unroll
        for (int lr = 0; lr < 3; ++lr) {
            int srow = R0 + lr; if (srow > H_ - 1) srow = H_ - 1;   // kern==0 kills clamp
            const float* xs = x + (((size_t)(b * C_ + cg * 8) * H_) + srow) * W_ + col;
            float v[8];
            #pragma unroll
            for (int j = 0; j < 8; ++j) v[j] = xs[(size_t)j * H_ * W_];
            unsigned int p0 = (unsigned int)f2bf(v[0]) | ((unsigned int)f2bf(v[1]) << 16);
            unsigned int p1 = (unsigned int)f2bf(v[2]) | ((unsigned int)f2bf(v[3]) << 16);
            unsigned int p2 = (unsigned int)f2bf(v[4]) | ((unsigned int)f2bf(v[5]) << 16);
            unsigned int p3 = (unsigned int)f2bf(v[6]) | ((unsigned int)f2bf(v[7]) << 16);
            int byte = ((lr * 128 + col) << 7) + cg * 16;
            *(uint4v*)((char*)xt + swz(byte)) = (uint4v){p0, p1, p2, p3};
        }
    }

    // ---------------- phase 0b: gaussian affinity kern, 9 slots ----------------
    for (int i = tid; i < 9 * 256; i += 1024) {
        int px = i & 255, gs = i >> 8;      // gs 0..8
        int py = px >> 7, xp = px & 127;
        int lhp = (gs < 3) ? 0 : 1;
        int ls  = (gs < 3) ? gs : gs - 3;
        int lntr = 1 + lhp;
        int wp, r, q;
        if (ls < lntr) { wp = 0; r = ls; q = 0; }
        else { int s = ls - lntr; wp = 1; r = s >> 1; q = s & 1; }
        int yp = R0 + py;
        int h = 2 * yp + lhp, w = 2 * xp + wp;
        int rr = yp + r, cl = xp + q;
        float kv = 0.f;
        if (rr < H_ && cl < W_) {
            int hh = rr * 2, ww = cl * 2;        // guide neighbor, always in-bounds
            const float* gb = guide + (size_t)b * 3 * GH_ * GW_;
            float s2 = 0.f;
            #pragma unroll
            for (int g = 0; g < 3; ++g) {
                float d = gb[(g * GH_ + hh) * GW_ + ww] - gb[(g * GH_ + h) * GW_ + w];
                s2 += d * d;
            }
            kv = __expf(-0.5f * s2);
        }
        klds[gs][py][xp] = kv;
    }
    __syncthreads();

    // ---------------- spin: wait for all 9 taps packed ----------------
    if (tid == 0) {
        while (__hip_atomic_load(&flags[1], __ATOMIC_ACQUIRE,
                                 __HIP_MEMORY_SCOPE_AGENT) < 9u)
            __builtin_amdgcn_s_sleep(8);
    }
    __syncthreads();

    // ---------------- phase 1: main MFMA loop ----------------
    const int wave = tid >> 6, lane = tid & 63;
    const int l16 = lane & 15, qk = lane >> 4;
    const int oh  = wave & 1;              // o half: 0..1 -> obase
    const int py  = (wave >> 1) & 1;
    const int xh  = (wave >> 2) & 1;       // x half: 0..1
    const int hp  = wave >> 3;             // 0..1
    const int obase = oh * 32;
    const int xpb   = xh * 64;
    const int yp = R0 + py;
    const int h  = 2 * yp + hp;
    const int ntr = 1 + hp;
    const int kbase = hp ? 3 : 0;

    for (int mf = 0; mf < 2; ++mf) {
        float acc0[4][4];   // wp=0 (w = 2xp)   [nf][e]
        float acc1[4][4];   // wp=1 (w = 2xp+1)
        #pragma unroll
        for (int nf = 0; nf < 4; ++nf)
            #pragma unroll
            for (int e = 0; e < 4; ++e) { acc0[nf][e] = 0.f; acc1[nf][e] = 0.f; }

        const int o = obase + mf * 16 + l16;

        for (int r = 0; r <= hp; ++r) {
            int kh = hp ? 2 * r : 1;
            int rowc = yp + r; if (rowc > H_ - 1) rowc = H_ - 1;
            int lr0 = rowc - R0;          // 0..2, local xt row
            int s_c = kbase + r;                  // wp0, kw=1
            int s_l = kbase + ntr + 2 * r;        // wp1, q=0, kw=0
            int s_r = kbase + ntr + 2 * r + 1;    // wp1, q=1, kw=2

            // A fragments for kw=0,1,2 at this kh (this mf only): A[m=o][k=c]
            short8 af[3][2];
            #pragma unroll
            for (int kw3 = 0; kw3 < 3; ++kw3) {
                const short8* wbase = (const short8*)(wtb + (size_t)(kh * 3 + kw3) * OC_ * C_);
                af[kw3][0] = wbase[(o * C_ + qk * 8) >> 3];
                af[kw3][1] = wbase[(o * C_ + 32 + qk * 8) >> 3];
            }

            #pragma unroll
            for (int nf = 0; nf < 4; ++nf) {
                int xp = xpb + nf * 16 + l16;
                int col1 = xp + 1; if (col1 > W_ - 1) col1 = W_ - 1;
                int base0 = ((lr0 * 128 + xp)   << 7) + qk * 16;
                int base1 = ((lr0 * 128 + col1) << 7) + qk * 16;
                short8 b0a = *(const short8*)((const char*)xt + swz(base0));
                short8 b0b = *(const short8*)((const char*)xt + swz(base0 + 64));
                short8 b1a = *(const short8*)((const char*)xt + swz(base1));
                short8 b1b = *(const short8*)((const char*)xt + swz(base1 + 64));
                float kc = klds[s_c][py][xp];
                float kl = klds[s_l][py][xp];
                float kr = klds[s_r][py][xp];
                float4v d;
                d = (float4v){0.f, 0.f, 0.f, 0.f};
                d = __builtin_amdgcn_mfma_f32_16x16x32_bf16(af[1][0], b0a, d, 0, 0, 0);
                d = __builtin_amdgcn_mfma_f32_16x16x32_bf16(af[1][1], b0b, d, 0, 0, 0);
                #pragma unroll
                for (int e = 0; e < 4; ++e) acc0[nf][e] += kc * d[e];
                d = (float4v){0.f, 0.f, 0.f, 0.f};
                d = __builtin_amdgcn_mfma_f32_16x16x32_bf16(af[0][0], b0a, d, 0, 0, 0);
                d = __builtin_amdgcn_mfma_f32_16x16x32_bf16(af[0][1], b0b, d, 0, 0, 0);
                #pragma unroll
                for (int e = 0; e < 4; ++e) acc1[nf][e] += kl * d[e];
                d = (float4v){0.f, 0.f, 0.f, 0.f};
                d = __builtin_amdgcn_mfma_f32_16x16x32_bf16(af[2][0], b1a, d, 0, 0, 0);
                d = __builtin_amdgcn_mfma_f32_16x16x32_bf16(af[2][1], b1b, d, 0, 0, 0);
                #pragma unroll
                for (int e = 0; e < 4; ++e) acc1[nf][e] += kr * d[e];
            }
        }

        // ---- epilogue for this mf: bias + contiguous float2 stores ----
        float bv[4];
        #pragma unroll
        for (int e = 0; e < 4; ++e)
            bv[e] = bias[obase + mf * 16 + qk * 4 + e];

        #pragma unroll
        for (int e = 0; e < 4; ++e) {
            int oo = obase + mf * 16 + qk * 4 + e;
            float2* op = (float2*)(out + (((size_t)b * OC_ + oo) * GH_ + h) * GW_);
            #pragma unroll
            for (int nf = 0; nf < 4; ++nf) {
                int xp = xpb + nf * 16 + l16;
                float2 v;
                v.x = acc0[nf][e] + bv[e];
                v.y = acc1[nf][e] + bv[e];
                op[xp] = v;
            }
        }
    }
}

extern "C" void kernel_launch(void* const* d_in, const int* in_sizes, int n_in,
                              void* d_out, int out_size, void* d_ws, size_t ws_size,
                              hipStream_t stream) {
    const float* x     = (const float*)d_in[0];
    const float* guide = (const float*)d_in[1];
    const float* wgt   = (const float*)d_in[2];
    const float* bias  = (const float*)d_in[3];
    float* out = (float*)d_out;

    unsigned short* wtb = (unsigned short*)d_ws;                    // 72 KB
    unsigned int* flags = (unsigned int*)((char*)d_ws + 9 * OC_ * C_ * sizeof(unsigned short));

    hipMemsetAsync(flags, 0, 16, stream);   // ticket + done counters (ws is poisoned)
    pac_fused<<<dim3(64, 4), 1024, 0, stream>>>(x, guide, wgt, bias, wtb, flags, out);
}

// Round 7
// 104.610 us; speedup vs baseline: 1.0430x; 1.0430x over previous
//
#include <hip/hip_runtime.h>
#include <math.h>

typedef __attribute__((ext_vector_type(8))) short short8;
typedef __attribute__((ext_vector_type(4))) float float4v;
typedef __attribute__((ext_vector_type(4))) unsigned int uint4v;

#define GH_ 256
#define GW_ 256
#define H_  128
#define W_  128
#define C_  64
#define OC_ 64

static __device__ __forceinline__ unsigned short f2bf(float f) {
    union { float f; unsigned int u; } v; v.f = f;
    unsigned int u = v.u;
    unsigned int r = u + 0x7FFFu + ((u >> 16) & 1u);   // round-to-nearest-even
    return (unsigned short)(r >> 16);
}

// XOR swizzle within each 128B row: spreads the per-row 128B stride across
// 8 16B bank-group slots. Applied identically on write and read (xt AND wl).
static __device__ __forceinline__ int swz(int byte) {
    return byte ^ (((byte >> 7) & 7) << 4);
}

// Single self-contained kernel: NO workspace, NO second dispatch, NO atomics.
// LDS (132096 B total, 1 block/CU on gfx950's 160 KiB):
//   xt   : 3 x-rows transposed to [lr][col][c] bf16, swizzled      (49152 B)
//   wl   : all 9 weight taps [t][o][c] bf16, swizzled              (73728 B)
//   klds : gaussian affinity, 9 slots (3 for hp=0, 6 for hp=1)     ( 9216 B)
// Phase 0 (no internal barriers): pack weights (scattered L2-hot reads),
// transpose x (coalesced HBM reads, one ds_write_b128 per thread per row),
// compute klds. One __syncthreads. Phase 1: 16 waves = (oh,py,xh,hp) MFMA.
__global__ __launch_bounds__(1024, 4) void pac_fused(
    const float* __restrict__ x,
    const float* __restrict__ guide,
    const float* __restrict__ wgt,
    const float* __restrict__ bias,
    float* __restrict__ out)
{
    __shared__ unsigned short xt[3 * 128 * 64];   // swizzled [lr][col][c]
    __shared__ unsigned short wl[9 * 64 * 64];    // swizzled [t][o][c]
    __shared__ float klds[9][2][128];

    const int ypair = blockIdx.x;   // 0..63
    const int b     = blockIdx.y;   // 0..3
    const int tid   = threadIdx.x;
    const int R0    = ypair * 2;

    // ---------------- phase 0a: weight pack -> LDS (all 9 taps) ----------------
    // 18432 packed-u32 elements: flat = (t, o, c2); reads are scattered but wgt
    // is 36 KB -> L2/L3-hot after the first blocks. LDS writes 2-way = free.
    #pragma unroll
    for (int j = 0; j < 18; ++j) {
        int flat = j * 1024 + tid;
        int c2 = flat & 31, o = (flat >> 5) & 63, t = flat >> 11;
        int c = c2 * 2;
        float lo = wgt[(c * OC_ + o) * 9 + t];
        float hi = wgt[((c + 1) * OC_ + o) * 9 + t];
        unsigned int pk = (unsigned int)f2bf(lo) | ((unsigned int)f2bf(hi) << 16);
        int byte = ((t * 64 + o) << 7) + c2 * 4;
        *(unsigned int*)((char*)wl + swz(byte)) = pk;
    }

    // ---------------- phase 0b: direct transpose x -> xt ----------------
    {
        const int col = tid & 127;          // source iw / xt row
        const int cg  = tid >> 7;           // channel group 0..7 (8 ch each)
        #pragma unroll
        for (int lr = 0; lr < 3; ++lr) {
            int srow = R0 + lr; if (srow > H_ - 1) srow = H_ - 1;   // kern==0 kills clamp
            const float* xs = x + (((size_t)(b * C_ + cg * 8) * H_) + srow) * W_ + col;
            float v[8];
            #pragma unroll
            for (int j = 0; j < 8; ++j) v[j] = xs[(size_t)j * H_ * W_];
            unsigned int p0 = (unsigned int)f2bf(v[0]) | ((unsigned int)f2bf(v[1]) << 16);
            unsigned int p1 = (unsigned int)f2bf(v[2]) | ((unsigned int)f2bf(v[3]) << 16);
            unsigned int p2 = (unsigned int)f2bf(v[4]) | ((unsigned int)f2bf(v[5]) << 16);
            unsigned int p3 = (unsigned int)f2bf(v[6]) | ((unsigned int)f2bf(v[7]) << 16);
            int byte = ((lr * 128 + col) << 7) + cg * 16;
            *(uint4v*)((char*)xt + swz(byte)) = (uint4v){p0, p1, p2, p3};
        }
    }

    // ---------------- phase 0c: gaussian affinity kern, 9 slots ----------------
    for (int i = tid; i < 9 * 256; i += 1024) {
        int px = i & 255, gs = i >> 8;      // gs 0..8
        int py = px >> 7, xp = px & 127;
        int lhp = (gs < 3) ? 0 : 1;
        int ls  = (gs < 3) ? gs : gs - 3;
        int lntr = 1 + lhp;
        int wp, r, q;
        if (ls < lntr) { wp = 0; r = ls; q = 0; }
        else { int s = ls - lntr; wp = 1; r = s >> 1; q = s & 1; }
        int yp = R0 + py;
        int h = 2 * yp + lhp, w = 2 * xp + wp;
        int rr = yp + r, cl = xp + q;
        float kv = 0.f;
        if (rr < H_ && cl < W_) {
            int hh = rr * 2, ww = cl * 2;        // guide neighbor, always in-bounds
            const float* gb = guide + (size_t)b * 3 * GH_ * GW_;
            float s2 = 0.f;
            #pragma unroll
            for (int g = 0; g < 3; ++g) {
                float d = gb[(g * GH_ + hh) * GW_ + ww] - gb[(g * GH_ + h) * GW_ + w];
                s2 += d * d;
            }
            kv = __expf(-0.5f * s2);
        }
        klds[gs][py][xp] = kv;
    }
    __syncthreads();

    // ---------------- phase 1: main MFMA loop ----------------
    const int wave = tid >> 6, lane = tid & 63;
    const int l16 = lane & 15, qk = lane >> 4;
    const int oh  = wave & 1;              // o half: 0..1 -> obase
    const int py  = (wave >> 1) & 1;
    const int xh  = (wave >> 2) & 1;       // x half: 0..1
    const int hp  = wave >> 3;             // 0..1
    const int obase = oh * 32;
    const int xpb   = xh * 64;
    const int yp = R0 + py;
    const int h  = 2 * yp + hp;
    const int ntr = 1 + hp;
    const int kbase = hp ? 3 : 0;

    for (int mf = 0; mf < 2; ++mf) {
        float acc0[4][4];   // wp=0 (w = 2xp)   [nf][e]
        float acc1[4][4];   // wp=1 (w = 2xp+1)
        #pragma unroll
        for (int nf = 0; nf < 4; ++nf)
            #pragma unroll
            for (int e = 0; e < 4; ++e) { acc0[nf][e] = 0.f; acc1[nf][e] = 0.f; }

        const int o = obase + mf * 16 + l16;

        for (int r = 0; r <= hp; ++r) {
            int kh = hp ? 2 * r : 1;
            int rowc = yp + r; if (rowc > H_ - 1) rowc = H_ - 1;
            int lr0 = rowc - R0;          // 0..2, local xt row
            int s_c = kbase + r;                  // wp0, kw=1
            int s_l = kbase + ntr + 2 * r;        // wp1, q=0, kw=0
            int s_r = kbase + ntr + 2 * r + 1;    // wp1, q=1, kw=2

            // A fragments for kw=0,1,2 at this kh (this mf only), from LDS wl
            short8 af[3][2];
            #pragma unroll
            for (int kw3 = 0; kw3 < 3; ++kw3) {
                int tb = ((kh * 3 + kw3) * 64 + o) << 7;   // [t][o] row base, bytes
                af[kw3][0] = *(const short8*)((const char*)wl + swz(tb + qk * 16));
                af[kw3][1] = *(const short8*)((const char*)wl + swz(tb + 64 + qk * 16));
            }

            #pragma unroll
            for (int nf = 0; nf < 4; ++nf) {
                int xp = xpb + nf * 16 + l16;
                int col1 = xp + 1; if (col1 > W_ - 1) col1 = W_ - 1;
                int base0 = ((lr0 * 128 + xp)   << 7) + qk * 16;
                int base1 = ((lr0 * 128 + col1) << 7) + qk * 16;
                short8 b0a = *(const short8*)((const char*)xt + swz(base0));
                short8 b0b = *(const short8*)((const char*)xt + swz(base0 + 64));
                short8 b1a = *(const short8*)((const char*)xt + swz(base1));
                short8 b1b = *(const short8*)((const char*)xt + swz(base1 + 64));
                float kc = klds[s_c][py][xp];
                float kl = klds[s_l][py][xp];
                float kr = klds[s_r][py][xp];
                float4v d;
                d = (float4v){0.f, 0.f, 0.f, 0.f};
                d = __builtin_amdgcn_mfma_f32_16x16x32_bf16(af[1][0], b0a, d, 0, 0, 0);
                d = __builtin_amdgcn_mfma_f32_16x16x32_bf16(af[1][1], b0b, d, 0, 0, 0);
                #pragma unroll
                for (int e = 0; e < 4; ++e) acc0[nf][e] += kc * d[e];
                d = (float4v){0.f, 0.f, 0.f, 0.f};
                d = __builtin_amdgcn_mfma_f32_16x16x32_bf16(af[0][0], b0a, d, 0, 0, 0);
                d = __builtin_amdgcn_mfma_f32_16x16x32_bf16(af[0][1], b0b, d, 0, 0, 0);
                #pragma unroll
                for (int e = 0; e < 4; ++e) acc1[nf][e] += kl * d[e];
                d = (float4v){0.f, 0.f, 0.f, 0.f};
                d = __builtin_amdgcn_mfma_f32_16x16x32_bf16(af[2][0], b1a, d, 0, 0, 0);
                d = __builtin_amdgcn_mfma_f32_16x16x32_bf16(af[2][1], b1b, d, 0, 0, 0);
                #pragma unroll
                for (int e = 0; e < 4; ++e) acc1[nf][e] += kr * d[e];
            }
        }

        // ---- epilogue for this mf: bias + contiguous float2 stores ----
        float bv[4];
        #pragma unroll
        for (int e = 0; e < 4; ++e)
            bv[e] = bias[obase + mf * 16 + qk * 4 + e];

        #pragma unroll
        for (int e = 0; e < 4; ++e) {
            int oo = obase + mf * 16 + qk * 4 + e;
            float2* op = (float2*)(out + (((size_t)b * OC_ + oo) * GH_ + h) * GW_);
            #pragma unroll
            for (int nf = 0; nf < 4; ++nf) {
                int xp = xpb + nf * 16 + l16;
                float2 v;
                v.x = acc0[nf][e] + bv[e];
                v.y = acc1[nf][e] + bv[e];
                op[xp] = v;
            }
        }
    }
}

extern "C" void kernel_launch(void* const* d_in, const int* in_sizes, int n_in,
                              void* d_out, int out_size, void* d_ws, size_t ws_size,
                              hipStream_t stream) {
    const float* x     = (const float*)d_in[0];
    const float* guide = (const float*)d_in[1];
    const float* wgt   = (const float*)d_in[2];
    const float* bias  = (const float*)d_in[3];
    float* out = (float*)d_out;
    (void)d_ws; (void)ws_size;   // workspace intentionally unused

    pac_fused<<<dim3(64, 4), 1024, 0, stream>>>(x, guide, wgt, bias, out);
}

// Round 8
// 103.849 us; speedup vs baseline: 1.0507x; 1.0073x over previous
//
#include <hip/hip_runtime.h>
#include <math.h>

typedef __attribute__((ext_vector_type(8))) short short8;
typedef __attribute__((ext_vector_type(4))) float float4v;
typedef __attribute__((ext_vector_type(4))) unsigned int uint4v;

#define GH_ 256
#define GW_ 256
#define H_  128
#define W_  128
#define C_  64
#define OC_ 64
#define NB_ 4

static __device__ __forceinline__ unsigned short f2bf(float f) {
    union { float f; unsigned int u; } v; v.f = f;
    unsigned int u = v.u;
    unsigned int r = u + 0x7FFFu + ((u >> 16) & 1u);   // round-to-nearest-even
    return (unsigned short)(r >> 16);
}

// XOR swizzle within each 128B "col row" of xt: spreads the per-col 128B stride
// across 8 16B bank-group slots. Applied identically on write and read.
static __device__ __forceinline__ int swz(int byte) {
    return byte ^ (((byte >> 7) & 7) << 4);
}

// Tiny weight pack: 9 blocks, one tap each.
// weight[c][o][kh][kw] fp32 -> wtb[t=kh*3+kw][o][c] bf16 (A-side)
__global__ __launch_bounds__(512) void prep_w(const float* __restrict__ w,
                                              unsigned short* __restrict__ wtb) {
    const int t = blockIdx.x;
    const int kh = t / 3, kw = t - kh * 3;
    for (int i = threadIdx.x; i < OC_ * C_; i += 512) {
        int c = i & 63, o = (i >> 6) & 63;
        wtb[t * OC_ * C_ + i] = f2bf(w[((c * OC_ + o) * 3 + kh) * 3 + kw]);
    }
}

// Fused main, 1024 threads, 1 block/CU, both hp halves per block.
// Phase 0: direct coalesced transpose x rows R0..R0+2 -> swizzled LDS xt
//          (one ds_write_b128 per thread per row, ZERO staging barriers),
//          + merged klds (9 slots: 3 for hp=0, 6 for hp=1). One barrier total.
// Phase 1: 16 waves = (oh, py, xh, hp); mf-outer MFMA loop, B-frags from LDS.
__global__ __launch_bounds__(1024, 4) void pac_fused(
    const float* __restrict__ x,
    const float* __restrict__ guide,
    const unsigned short* __restrict__ wtb,
    const float* __restrict__ bias,
    float* __restrict__ out)
{
    __shared__ unsigned short xt[3 * 128 * 64];   // 49152 B, swizzled [lr][col][c] bf16
    __shared__ float klds[9][2][128];             // 9216 B

    const int ypair = blockIdx.x;   // 0..63
    const int b     = blockIdx.y;   // 0..3
    const int tid   = threadIdx.x;
    const int R0    = ypair * 2;

    // ---------------- phase 0a: direct transpose x -> xt ----------------
    {
        const int col = tid & 127;          // source iw / xt row
        const int cg  = tid >> 7;           // channel group 0..7 (8 ch each)
        #pragma unroll
        for (int lr = 0; lr < 3; ++lr) {
            int srow = R0 + lr; if (srow > H_ - 1) srow = H_ - 1;   // kern==0 kills clamp
            const float* xs = x + (((size_t)(b * C_ + cg * 8) * H_) + srow) * W_ + col;
            float v[8];
            #pragma unroll
            for (int j = 0; j < 8; ++j) v[j] = xs[(size_t)j * H_ * W_];
            unsigned int p0 = (unsigned int)f2bf(v[0]) | ((unsigned int)f2bf(v[1]) << 16);
            unsigned int p1 = (unsigned int)f2bf(v[2]) | ((unsigned int)f2bf(v[3]) << 16);
            unsigned int p2 = (unsigned int)f2bf(v[4]) | ((unsigned int)f2bf(v[5]) << 16);
            unsigned int p3 = (unsigned int)f2bf(v[6]) | ((unsigned int)f2bf(v[7]) << 16);
            int byte = ((lr * 128 + col) << 7) + cg * 16;
            *(uint4v*)((char*)xt + swz(byte)) = (uint4v){p0, p1, p2, p3};
        }
    }

    // ---------------- phase 0b: gaussian affinity kern, 9 slots ----------------
    for (int i = tid; i < 9 * 256; i += 1024) {
        int px = i & 255, gs = i >> 8;      // gs 0..8
        int py = px >> 7, xp = px & 127;
        int lhp = (gs < 3) ? 0 : 1;
        int ls  = (gs < 3) ? gs : gs - 3;
        int lntr = 1 + lhp;
        int wp, r, q;
        if (ls < lntr) { wp = 0; r = ls; q = 0; }
        else { int s = ls - lntr; wp = 1; r = s >> 1; q = s & 1; }
        int yp = R0 + py;
        int h = 2 * yp + lhp, w = 2 * xp + wp;
        int rr = yp + r, cl = xp + q;
        float kv = 0.f;
        if (rr < H_ && cl < W_) {
            int hh = rr * 2, ww = cl * 2;        // guide neighbor, always in-bounds
            const float* gb = guide + (size_t)b * 3 * GH_ * GW_;
            float s2 = 0.f;
            #pragma unroll
            for (int g = 0; g < 3; ++g) {
                float d = gb[(g * GH_ + hh) * GW_ + ww] - gb[(g * GH_ + h) * GW_ + w];
                s2 += d * d;
            }
            kv = __expf(-0.5f * s2);
        }
        klds[gs][py][xp] = kv;
    }
    __syncthreads();

    // ---------------- phase 1: main MFMA loop ----------------
    const int wave = tid >> 6, lane = tid & 63;
    const int l16 = lane & 15, qk = lane >> 4;
    const int oh  = wave & 1;              // o half: 0..1 -> obase
    const int py  = (wave >> 1) & 1;
    const int xh  = (wave >> 2) & 1;       // x half: 0..1
    const int hp  = wave >> 3;             // 0..1
    const int obase = oh * 32;
    const int xpb   = xh * 64;
    const int yp = R0 + py;
    const int h  = 2 * yp + hp;
    const int ntr = 1 + hp;
    const int kbase = hp ? 3 : 0;

    for (int mf = 0; mf < 2; ++mf) {
        float acc0[4][4];   // wp=0 (w = 2xp)   [nf][e]
        float acc1[4][4];   // wp=1 (w = 2xp+1)
        #pragma unroll
        for (int nf = 0; nf < 4; ++nf)
            #pragma unroll
            for (int e = 0; e < 4; ++e) { acc0[nf][e] = 0.f; acc1[nf][e] = 0.f; }

        const int o = obase + mf * 16 + l16;

        for (int r = 0; r <= hp; ++r) {
            int kh = hp ? 2 * r : 1;
            int rowc = yp + r; if (rowc > H_ - 1) rowc = H_ - 1;
            int lr0 = rowc - R0;          // 0..2, local xt row
            int s_c = kbase + r;                  // wp0, kw=1
            int s_l = kbase + ntr + 2 * r;        // wp1, q=0, kw=0
            int s_r = kbase + ntr + 2 * r + 1;    // wp1, q=1, kw=2

            // A fragments for kw=0,1,2 at this kh (this mf only): A[m=o][k=c]
            short8 af[3][2];
            #pragma unroll
            for (int kw3 = 0; kw3 < 3; ++kw3) {
                const short8* wbase = (const short8*)(wtb + (size_t)(kh * 3 + kw3) * OC_ * C_);
                af[kw3][0] = wbase[(o * C_ + qk * 8) >> 3];
                af[kw3][1] = wbase[(o * C_ + 32 + qk * 8) >> 3];
            }

            #pragma unroll
            for (int nf = 0; nf < 4; ++nf) {
                int xp = xpb + nf * 16 + l16;
                int col1 = xp + 1; if (col1 > W_ - 1) col1 = W_ - 1;
                int base0 = ((lr0 * 128 + xp)   << 7) + qk * 16;
                int base1 = ((lr0 * 128 + col1) << 7) + qk * 16;
                short8 b0a = *(const short8*)((const char*)xt + swz(base0));
                short8 b0b = *(const short8*)((const char*)xt + swz(base0 + 64));
                short8 b1a = *(const short8*)((const char*)xt + swz(base1));
                short8 b1b = *(const short8*)((const char*)xt + swz(base1 + 64));
                float kc = klds[s_c][py][xp];
                float kl = klds[s_l][py][xp];
                float kr = klds[s_r][py][xp];
                float4v d;
                d = (float4v){0.f, 0.f, 0.f, 0.f};
                d = __builtin_amdgcn_mfma_f32_16x16x32_bf16(af[1][0], b0a, d, 0, 0, 0);
                d = __builtin_amdgcn_mfma_f32_16x16x32_bf16(af[1][1], b0b, d, 0, 0, 0);
                #pragma unroll
                for (int e = 0; e < 4; ++e) acc0[nf][e] += kc * d[e];
                d = (float4v){0.f, 0.f, 0.f, 0.f};
                d = __builtin_amdgcn_mfma_f32_16x16x32_bf16(af[0][0], b0a, d, 0, 0, 0);
                d = __builtin_amdgcn_mfma_f32_16x16x32_bf16(af[0][1], b0b, d, 0, 0, 0);
                #pragma unroll
                for (int e = 0; e < 4; ++e) acc1[nf][e] += kl * d[e];
                d = (float4v){0.f, 0.f, 0.f, 0.f};
                d = __builtin_amdgcn_mfma_f32_16x16x32_bf16(af[2][0], b1a, d, 0, 0, 0);
                d = __builtin_amdgcn_mfma_f32_16x16x32_bf16(af[2][1], b1b, d, 0, 0, 0);
                #pragma unroll
                for (int e = 0; e < 4; ++e) acc1[nf][e] += kr * d[e];
            }
        }

        // ---- epilogue for this mf: bias + contiguous float2 stores ----
        float bv[4];
        #pragma unroll
        for (int e = 0; e < 4; ++e)
            bv[e] = bias[obase + mf * 16 + qk * 4 + e];

        #pragma unroll
        for (int e = 0; e < 4; ++e) {
            int oo = obase + mf * 16 + qk * 4 + e;
            float2* op = (float2*)(out + (((size_t)b * OC_ + oo) * GH_ + h) * GW_);
            #pragma unroll
            for (int nf = 0; nf < 4; ++nf) {
                int xp = xpb + nf * 16 + l16;
                float2 v;
                v.x = acc0[nf][e] + bv[e];
                v.y = acc1[nf][e] + bv[e];
                op[xp] = v;
            }
        }
    }
}

extern "C" void kernel_launch(void* const* d_in, const int* in_sizes, int n_in,
                              void* d_out, int out_size, void* d_ws, size_t ws_size,
                              hipStream_t stream) {
    const float* x     = (const float*)d_in[0];
    const float* guide = (const float*)d_in[1];
    const float* wgt   = (const float*)d_in[2];
    const float* bias  = (const float*)d_in[3];
    float* out = (float*)d_out;

    unsigned short* wtb = (unsigned short*)d_ws;   // 72 KB only

    prep_w<<<dim3(9), 512, 0, stream>>>(wgt, wtb);
    pac_fused<<<dim3(64, 4), 1024, 0, stream>>>(x, guide, wtb, bias, out);
}